// Round 1
// baseline (38972.879 us; speedup 1.0000x reference)
//
#include <hip/hip_runtime.h>
#include <cstddef>
#include <cstdint>
#include <cmath>

// Problem constants
#define Bq 64
#define Tq 512
#define Hq 512
#define Eq 128
#define Vq 2048
#define KXq 1152   // E + 2H (gates GEMM K)
#define KSq 1024   // 2H    (score GEMM K)

// ---------------------------------------------------------------------------
// K0: one-time init per call: lengths -> ctx0, emb0 = 0, transpose W_attn
// ---------------------------------------------------------------------------
__global__ __launch_bounds__(256) void k0_init(
    const float* __restrict__ enc, const int* __restrict__ mask,
    const float* __restrict__ Wa, float* __restrict__ WT,
    float* __restrict__ emb, float* __restrict__ ctx)
{
    const int blk = blockIdx.x;
    const int tid = threadIdx.x;
    if (blk < 64) {
        const int b = blk;
        __shared__ int red[256];
        int s = mask[b * Tq + tid] + mask[b * Tq + 256 + tid];
        red[tid] = s;
        __syncthreads();
        for (int off = 128; off; off >>= 1) {
            if (tid < off) red[tid] += red[tid + off];
            __syncthreads();
        }
        int len = red[0];
        int tlast = len - 1;
        if (tlast < 0) tlast = 0;
        const float* src = enc + ((size_t)(b * Tq + tlast)) * Hq;
        ctx[b * Hq + tid]       = src[tid];
        ctx[b * Hq + 256 + tid] = src[256 + tid];
        if (tid < Eq) emb[b * Eq + tid] = 0.0f;
    } else {
        // transpose W_attn [k][h] -> WT [h][k]
        const int j = blk - 64;   // k-slab of 8
        for (int kk = j * 8; kk < j * 8 + 8; ++kk) {
            float a0 = Wa[(size_t)kk * Hq + tid];
            float a1 = Wa[(size_t)kk * Hq + 256 + tid];
            WT[(size_t)tid * Hq + kk]         = a0;
            WT[(size_t)(256 + tid) * Hq + kk] = a1;
        }
    }
}

// ---------------------------------------------------------------------------
// K1: gates GEMM (i,g,o only; f-gate is dead since c0=0) + LSTM activations
// grid 256 blocks x 512 thr; block handles hdn columns k0=2*blk, k0+1 for all b
// thread: b = tid>>3 (64), q = tid&7 (8-way K split)
// ---------------------------------------------------------------------------
__global__ __launch_bounds__(512) void k1_gates(
    const float* __restrict__ enc, const float* __restrict__ emb,
    const float* __restrict__ ctx, const float* __restrict__ Wih,
    const float* __restrict__ bih, const float* __restrict__ bhh,
    float* __restrict__ hdn, int t)
{
    const int tid = threadIdx.x;
    const int b = tid >> 3, q = tid & 7;
    const int k0 = blockIdx.x * 2, k1 = k0 + 1;

    const float* wi0 = Wih + (size_t)(k0)        * KXq;
    const float* wg0 = Wih + (size_t)(1024 + k0) * KXq;
    const float* wo0 = Wih + (size_t)(1536 + k0) * KXq;
    const float* wi1 = Wih + (size_t)(k1)        * KXq;
    const float* wg1 = Wih + (size_t)(1024 + k1) * KXq;
    const float* wo1 = Wih + (size_t)(1536 + k1) * KXq;

    const float* embb = emb + b * Eq;
    const float* ctxb = ctx + b * Hq;
    const float* encb = enc + ((size_t)(b * Tq + t)) * Hq;

    float si0 = 0.f, sg0 = 0.f, so0 = 0.f, si1 = 0.f, sg1 = 0.f, so1 = 0.f;

    for (int j = 0; j < 36; ++j) {
        const int kk = j * 32 + q * 4;
        float4 x;
        if (kk < 128)       x = *(const float4*)(embb + kk);
        else if (kk < 640)  x = *(const float4*)(ctxb + (kk - 128));
        else                x = *(const float4*)(encb + (kk - 640));
        float4 w;
        w = *(const float4*)(wi0 + kk); si0 += w.x*x.x + w.y*x.y + w.z*x.z + w.w*x.w;
        w = *(const float4*)(wg0 + kk); sg0 += w.x*x.x + w.y*x.y + w.z*x.z + w.w*x.w;
        w = *(const float4*)(wo0 + kk); so0 += w.x*x.x + w.y*x.y + w.z*x.z + w.w*x.w;
        w = *(const float4*)(wi1 + kk); si1 += w.x*x.x + w.y*x.y + w.z*x.z + w.w*x.w;
        w = *(const float4*)(wg1 + kk); sg1 += w.x*x.x + w.y*x.y + w.z*x.z + w.w*x.w;
        w = *(const float4*)(wo1 + kk); so1 += w.x*x.x + w.y*x.y + w.z*x.z + w.w*x.w;
    }
    // reduce over q (lane bits 0..2, wave-local)
    for (int off = 1; off < 8; off <<= 1) {
        si0 += __shfl_xor(si0, off);
        sg0 += __shfl_xor(sg0, off);
        so0 += __shfl_xor(so0, off);
        si1 += __shfl_xor(si1, off);
        sg1 += __shfl_xor(sg1, off);
        so1 += __shfl_xor(so1, off);
    }
    if (q == 0) {
        float i0 = si0 + bih[k0]        + bhh[k0];
        float g0 = sg0 + bih[1024 + k0] + bhh[1024 + k0];
        float o0 = so0 + bih[1536 + k0] + bhh[1536 + k0];
        float i1 = si1 + bih[k1]        + bhh[k1];
        float g1 = sg1 + bih[1024 + k1] + bhh[1024 + k1];
        float o1 = so1 + bih[1536 + k1] + bhh[1536 + k1];
        float c0 = (1.0f / (1.0f + expf(-i0))) * tanhf(g0);
        float c1 = (1.0f / (1.0f + expf(-i1))) * tanhf(g1);
        float h0 = (1.0f / (1.0f + expf(-o0))) * tanhf(c0);
        float h1 = (1.0f / (1.0f + expf(-o1))) * tanhf(c1);
        hdn[b * Hq + k0] = h0;
        hdn[b * Hq + k1] = h1;
    }
}

// ---------------------------------------------------------------------------
// K2: scores = [hdn|ctx] @ W_out^T + b_out  (blocks 0..255, 8 V-cols each)
//     v = W_attn^T @ hdn (via WT)           (blocks 256..319, 8 h-cols each)
// ---------------------------------------------------------------------------
__global__ __launch_bounds__(512) void k2_scores_v(
    const float* __restrict__ hdn, const float* __restrict__ ctx,
    const float* __restrict__ Wout, const float* __restrict__ bout,
    const float* __restrict__ WT, float* __restrict__ sc, float* __restrict__ vv)
{
    const int tid = threadIdx.x;
    const int b = tid >> 3, q = tid & 7;

    if (blockIdx.x < 256) {
        const int c0 = blockIdx.x * 8;
        float acc[8];
        #pragma unroll
        for (int cc = 0; cc < 8; ++cc) acc[cc] = 0.f;
        const float* hb = hdn + b * Hq;
        const float* cb = ctx + b * Hq;
        for (int j = 0; j < 32; ++j) {
            const int kk = j * 32 + q * 4;
            float4 x = (kk < 512) ? *(const float4*)(hb + kk)
                                  : *(const float4*)(cb + (kk - 512));
            #pragma unroll
            for (int cc = 0; cc < 8; ++cc) {
                float4 w = *(const float4*)(Wout + (size_t)(c0 + cc) * KSq + kk);
                acc[cc] += w.x*x.x + w.y*x.y + w.z*x.z + w.w*x.w;
            }
        }
        #pragma unroll
        for (int cc = 0; cc < 8; ++cc)
            for (int off = 1; off < 8; off <<= 1)
                acc[cc] += __shfl_xor(acc[cc], off);
        if (q == 0) {
            #pragma unroll
            for (int cc = 0; cc < 8; ++cc)
                sc[b * Vq + c0 + cc] = acc[cc] + bout[c0 + cc];
        }
    } else {
        const int c0 = (blockIdx.x - 256) * 8;
        float acc[8];
        #pragma unroll
        for (int cc = 0; cc < 8; ++cc) acc[cc] = 0.f;
        const float* hb = hdn + b * Hq;
        for (int j = 0; j < 16; ++j) {
            const int kk = j * 32 + q * 4;
            float4 x = *(const float4*)(hb + kk);
            #pragma unroll
            for (int cc = 0; cc < 8; ++cc) {
                float4 w = *(const float4*)(WT + (size_t)(c0 + cc) * Hq + kk);
                acc[cc] += w.x*x.x + w.y*x.y + w.z*x.z + w.w*x.w;
            }
        }
        #pragma unroll
        for (int cc = 0; cc < 8; ++cc)
            for (int off = 1; off < 8; off <<= 1)
                acc[cc] += __shfl_xor(acc[cc], off);
        if (q == 0) {
            #pragma unroll
            for (int cc = 0; cc < 8; ++cc)
                vv[b * Hq + c0 + cc] = acc[cc];
        }
    }
}

// ---------------------------------------------------------------------------
// K3: blocks 0..63  : per-b logsumexp + argmax over V, write logp row, emb feed
//     blocks 64..319: flash attention partials (4 blocks per b, 128 t-rows each)
// ---------------------------------------------------------------------------
__global__ __launch_bounds__(512) void k3_reduce_flash(
    const float* __restrict__ enc, const int* __restrict__ mask,
    const float* __restrict__ sc, const float* __restrict__ vv,
    const float* __restrict__ embTab, float* __restrict__ emb,
    float* __restrict__ out, float* __restrict__ parts, int t)
{
    __shared__ float smem[8 * 512 + 32];
    const int tid = threadIdx.x;

    if (blockIdx.x < 64) {
        const int b = blockIdx.x;
        const float* sb = sc + b * Vq;
        float sv[4];
        float vmax = -3.4e38f;
        int vidx = 0;
        #pragma unroll
        for (int jj = 0; jj < 4; ++jj) {
            const int c = tid + (jj << 9);
            sv[jj] = sb[c];
            if (sv[jj] > vmax) { vmax = sv[jj]; vidx = c; }
        }
        float* sred = smem;
        int*   sidx = (int*)(smem + 512);
        sred[tid] = vmax; sidx[tid] = vidx;
        __syncthreads();
        for (int off = 256; off; off >>= 1) {
            if (tid < off) {
                float ov = sred[tid + off]; int oi = sidx[tid + off];
                if (ov > sred[tid] || (ov == sred[tid] && oi < sidx[tid])) {
                    sred[tid] = ov; sidx[tid] = oi;
                }
            }
            __syncthreads();
        }
        const float gmax = sred[0];
        const int   amax = sidx[0];
        __syncthreads();
        float psum = 0.f;
        #pragma unroll
        for (int jj = 0; jj < 4; ++jj) psum += expf(sv[jj] - gmax);
        sred[tid] = psum;
        __syncthreads();
        for (int off = 256; off; off >>= 1) {
            if (tid < off) sred[tid] += sred[tid + off];
            __syncthreads();
        }
        const float lse = gmax + logf(sred[0]);
        float* ob = out + ((size_t)(b * Tq + t)) * Vq;
        #pragma unroll
        for (int jj = 0; jj < 4; ++jj) {
            const int c = tid + (jj << 9);
            ob[c] = sv[jj] - lse;
        }
        if (tid < Eq) emb[b * Eq + tid] = embTab[(size_t)amax * Eq + tid];
    } else {
        const int fb = blockIdx.x - 64;
        const int b = fb >> 2, r = fb & 3;
        const int w = tid >> 6, lane = tid & 63;
        const float* vb = vv + b * Hq;
        float4 v0 = *(const float4*)(vb + lane * 4);
        float4 v1 = *(const float4*)(vb + 256 + lane * 4);
        float m = -3.4e38f, s = 0.f;
        float4 a0 = {0.f, 0.f, 0.f, 0.f}, a1 = {0.f, 0.f, 0.f, 0.f};
        const int tbase = r * 128 + w * 16;
        for (int jj = 0; jj < 16; ++jj) {
            const int tt = tbase + jj;
            if (!mask[b * Tq + tt]) continue;
            const float* er = enc + ((size_t)(b * Tq + tt)) * Hq;
            float4 e0 = *(const float4*)(er + lane * 4);
            float4 e1 = *(const float4*)(er + 256 + lane * 4);
            float d = e0.x*v0.x + e0.y*v0.y + e0.z*v0.z + e0.w*v0.w
                    + e1.x*v1.x + e1.y*v1.y + e1.z*v1.z + e1.w*v1.w;
            #pragma unroll
            for (int off = 1; off < 64; off <<= 1) d += __shfl_xor(d, off);
            const float mn = fmaxf(m, d);
            const float cs = expf(m - mn);
            const float p  = expf(d - mn);
            s = s * cs + p;
            a0.x = a0.x * cs + p * e0.x;  a0.y = a0.y * cs + p * e0.y;
            a0.z = a0.z * cs + p * e0.z;  a0.w = a0.w * cs + p * e0.w;
            a1.x = a1.x * cs + p * e1.x;  a1.y = a1.y * cs + p * e1.y;
            a1.z = a1.z * cs + p * e1.z;  a1.w = a1.w * cs + p * e1.w;
            m = mn;
        }
        // combine 8 waves in LDS
        float* la = smem;                 // [8][512]
        float* lm = smem + 8 * 512;       // [8]
        float* ls = lm + 8;               // [8]
        if (lane == 0) { lm[w] = m; ls[w] = s; }
        *(float4*)(la + w * 512 + lane * 4)       = a0;
        *(float4*)(la + w * 512 + 256 + lane * 4) = a1;
        __syncthreads();
        float M = lm[0];
        #pragma unroll
        for (int i = 1; i < 8; ++i) M = fmaxf(M, lm[i]);
        float stot = 0.f;
        #pragma unroll
        for (int i = 0; i < 8; ++i) stot += ls[i] * expf(lm[i] - M);
        float* pb = parts + (size_t)(b * 4 + r) * 528;
        if (tid == 0) { pb[0] = M; pb[1] = stot; }
        float acch = 0.f;
        #pragma unroll
        for (int ww = 0; ww < 8; ++ww) acch += la[ww * 512 + tid] * expf(lm[ww] - M);
        pb[16 + tid] = acch;
    }
}

// ---------------------------------------------------------------------------
// K4: combine 4 flash partials per b -> ctx_next
// ---------------------------------------------------------------------------
__global__ __launch_bounds__(256) void k4_ctx(
    const float* __restrict__ parts, const float* __restrict__ enc,
    float* __restrict__ ctx)
{
    const int b = blockIdx.x, tid = threadIdx.x;
    const float* pb = parts + (size_t)b * 4 * 528;
    const float m0 = pb[0], m1 = pb[528], m2 = pb[1056], m3 = pb[1584];
    const float M = fmaxf(fmaxf(m0, m1), fmaxf(m2, m3));
    const float e0 = expf(m0 - M), e1 = expf(m1 - M), e2 = expf(m2 - M), e3 = expf(m3 - M);
    const float stot = pb[1] * e0 + pb[529] * e1 + pb[1057] * e2 + pb[1585] * e3;
    if (stot > 0.f) {
        const float inv = 1.0f / stot;
        for (int h = tid; h < Hq; h += 256) {
            float a = pb[16 + h] * e0 + pb[528 + 16 + h] * e1
                    + pb[1056 + 16 + h] * e2 + pb[1584 + 16 + h] * e3;
            ctx[b * Hq + h] = a * inv;
        }
    } else {
        // fully-masked row: reference softmax(-1e12 everywhere) is uniform
        for (int h = tid; h < Hq; h += 256) {
            float a = 0.f;
            for (int tt = 0; tt < Tq; ++tt) a += enc[((size_t)(b * Tq + tt)) * Hq + h];
            ctx[b * Hq + h] = a / (float)Tq;
        }
    }
}

// ---------------------------------------------------------------------------
extern "C" void kernel_launch(void* const* d_in, const int* in_sizes, int n_in,
                              void* d_out, int out_size, void* d_ws, size_t ws_size,
                              hipStream_t stream)
{
    const float* enc    = (const float*)d_in[0];
    const int*   mask   = (const int*)  d_in[1];
    const float* embTab = (const float*)d_in[2];
    const float* Wih    = (const float*)d_in[3];
    const float* bih    = (const float*)d_in[4];
    const float* bhh    = (const float*)d_in[5];
    const float* Wa     = (const float*)d_in[6];
    // d_in[7] = b_attn: provably cancelled by softmax (constant over t)
    const float* Wout   = (const float*)d_in[8];
    const float* bout   = (const float*)d_in[9];
    float* out = (float*)d_out;
    float* ws  = (float*)d_ws;

    float* WT    = ws;                 // 262144 : W_attn transposed [h][k]
    float* emb   = WT + 262144;        // 8192   : current embedding feed [B][E]
    float* ctx   = emb + 8192;         // 32768  : current context [B][H]
    float* hdn   = ctx + 32768;        // 32768  : LSTM hidden [B][H]
    float* vv    = hdn + 32768;        // 32768  : W_attn^T @ hdn [B][H]
    float* sc    = vv + 32768;         // 131072 : raw scores [B][V]
    float* parts = sc + 131072;        // 135168 : flash partials [B][4][528]

    hipLaunchKernelGGL(k0_init, dim3(128), dim3(256), 0, stream,
                       enc, mask, Wa, WT, emb, ctx);

    for (int t = 0; t < Tq; ++t) {
        hipLaunchKernelGGL(k1_gates, dim3(256), dim3(512), 0, stream,
                           enc, emb, ctx, Wih, bih, bhh, hdn, t);
        hipLaunchKernelGGL(k2_scores_v, dim3(320), dim3(512), 0, stream,
                           hdn, ctx, Wout, bout, WT, sc, vv);
        hipLaunchKernelGGL(k3_reduce_flash, dim3(320), dim3(512), 0, stream,
                           enc, mask, sc, vv, embTab, emb, out, parts, t);
        hipLaunchKernelGGL(k4_ctx, dim3(64), dim3(256), 0, stream,
                           parts, enc, ctx);
    }
}